// Round 8
// baseline (285.317 us; speedup 1.0000x reference)
//
#include <hip/hip_runtime.h>

typedef _Float16 f16_t;
typedef _Float16 f16x2 __attribute__((ext_vector_type(2)));
typedef _Float16 f16x8 __attribute__((ext_vector_type(8)));
typedef float floatx4 __attribute__((ext_vector_type(4)));
typedef unsigned int u32;
typedef const __attribute__((address_space(1))) unsigned int* gptr_as1;
typedef __attribute__((address_space(3))) unsigned int* lptr_as3;

#define B_ 8
#define C_ 512
#define L_ 2048
#define D_ 1024
#define H_ 16

static __device__ __forceinline__ f16x2 bc2(u32 v) { return __builtin_bit_cast(f16x2, v); }
static __device__ __forceinline__ u32 cb2(f16x2 v) { return __builtin_bit_cast(u32, v); }

// ---------------------------------------------------------------------------
// Transpose + f32->f16 convert: in (R,C) f32 -> out (C,R) f16, batched z.
// ---------------------------------------------------------------------------
__global__ __launch_bounds__(256) void _MSA1_ktransf2h(const float* __restrict__ in,
                                                       f16_t* __restrict__ out,
                                                       int R, int C) {
  size_t zoff = (size_t)blockIdx.z * R * C;
  in += zoff; out += zoff;
  __shared__ f16_t tile[64][65];
  int r0 = blockIdx.y * 64, c0 = blockIdx.x * 64;
  int t = threadIdx.x;
  #pragma unroll
  for (int i = 0; i < 16; ++i) {
    int idx = t + i * 256;
    int r = idx >> 6, c = idx & 63;
    tile[c][r] = (f16_t)in[(size_t)(r0 + r) * C + (c0 + c)];
  }
  __syncthreads();
  #pragma unroll
  for (int i = 0; i < 16; ++i) {
    int idx = t + i * 256;
    int r = idx >> 6, c = idx & 63;
    out[(size_t)(c0 + r) * R + (r0 + c)] = tile[r][c];
  }
}

// ---------------------------------------------------------------------------
// Fused prep: all 4 weight transposes (f32->f16) + bias concat, one launch.
// ---------------------------------------------------------------------------
__global__ __launch_bounds__(256) void _MSA1_kprep(
    const float* __restrict__ wq, const float* __restrict__ wk,
    const float* __restrict__ wv, const float* __restrict__ wo,
    const float* __restrict__ bq, const float* __restrict__ bk,
    const float* __restrict__ bv,
    f16_t* __restrict__ wT3, f16_t* __restrict__ woT, float* __restrict__ bias3) {
  const int x = blockIdx.x, y = blockIdx.y;
  const int t = threadIdx.x;
  if (x == 128) {
    if (y == 0) {
      for (int i = t; i < 1024; i += 256) {
        bias3[i] = bq[i];
        bias3[1024 + i] = bk[i];
        bias3[2048 + i] = bv[i];
      }
    }
    return;
  }
  __shared__ f16_t tile[64][65];
  const float* in; f16_t* out; int R, C, r0, c0;
  if (y < 3) {
    R = 512; C = 1024;
    in = (y == 0) ? wq : (y == 1) ? wk : wv;
    out = wT3 + (size_t)y * 524288;
    r0 = (x >> 4) * 64; c0 = (x & 15) * 64;
  } else {
    R = 1024; C = 512;
    in = wo; out = woT;
    r0 = (x >> 3) * 64; c0 = (x & 7) * 64;
  }
  #pragma unroll
  for (int i = 0; i < 16; ++i) {
    int idx = t + i * 256;
    int r = idx >> 6, c = idx & 63;
    tile[c][r] = (f16_t)in[(size_t)(r0 + r) * C + (c0 + c)];
  }
  __syncthreads();
  #pragma unroll
  for (int i = 0; i < 16; ++i) {
    int idx = t + i * 256;
    int r = idx >> 6, c = idx & 63;
    out[(size_t)(c0 + r) * R + (r0 + c)] = tile[r][c];
  }
}

// ---------------------------------------------------------------------------
// GEMM (round-5 best): out[m][n] = sum_k A[m][k]*Bt[n][k] + bias[m]
// 128x128 tile, BK=32, 4 waves x 64x64, 16x16x32 f16 MFMA, global_load_lds
// width-16 staging, epilogue LDS aliases staging (union) -> 33.8 KB, 4 blk/CU.
// ---------------------------------------------------------------------------
template <bool F32OUT, int K>
__global__ __launch_bounds__(256) void _MSA1_kgemm(
    const f16_t* __restrict__ A, const f16_t* __restrict__ Bt,
    const float* __restrict__ bias, void* __restrict__ Cdv,
    int M, int N, long sA, long sB, long sC) {
  A  += (size_t)blockIdx.z * sA;
  Bt += (size_t)blockIdx.z * sB;
  const int m0 = blockIdx.y * 128, n0 = blockIdx.x * 128;

  union ShU {
    struct { f16_t As[128][32]; f16_t Bs[128][32]; } ab;   // 16 KB
    f16_t Ep[F32OUT ? 1 : 128][132];                        // 33.8 KB (f16 path)
  };
  __shared__ ShU sh;

  const int t = threadIdx.x;
  const int lane = t & 63, w = t >> 6;
  const int mh = (w & 1) * 64, nh = (w >> 1) * 64;
  const int fm = lane & 15, fq = lane >> 4;
  const int srcoff = ((t & 3) ^ ((t >> 2) & 3)) * 8;
  const int colf = ((fq ^ (fm & 3)) * 8);

  floatx4 acc[4][4];
  #pragma unroll
  for (int i = 0; i < 4; ++i)
    #pragma unroll
    for (int j = 0; j < 4; ++j) {
      floatx4 z4 = {0.f, 0.f, 0.f, 0.f};
      acc[i][j] = z4;
    }

  for (int kt = 0; kt < K; kt += 32) {
    __syncthreads();
    #pragma unroll
    for (int j = 0; j < 2; ++j) {
      int chunk = j * 256 + t;
      int r = chunk >> 2;
      const f16_t* ga = A + (size_t)(m0 + r) * K + kt + srcoff;
      __builtin_amdgcn_global_load_lds((gptr_as1)(const void*)ga,
          (lptr_as3)(void*)((char*)&sh.ab.As[0][0] + j * 4096 + w * 1024), 16, 0, 0);
      const f16_t* gb = Bt + (size_t)(n0 + r) * K + kt + srcoff;
      __builtin_amdgcn_global_load_lds((gptr_as1)(const void*)gb,
          (lptr_as3)(void*)((char*)&sh.ab.Bs[0][0] + j * 4096 + w * 1024), 16, 0, 0);
    }
    __syncthreads();

    f16x8 af[4], bfr[4];
    #pragma unroll
    for (int mt = 0; mt < 4; ++mt)
      af[mt] = *(const f16x8*)&sh.ab.As[mh + mt * 16 + fm][colf];
    #pragma unroll
    for (int nt = 0; nt < 4; ++nt)
      bfr[nt] = *(const f16x8*)&sh.ab.Bs[nh + nt * 16 + fm][colf];
    #pragma unroll
    for (int mt = 0; mt < 4; ++mt)
      #pragma unroll
      for (int nt = 0; nt < 4; ++nt)
        acc[mt][nt] = __builtin_amdgcn_mfma_f32_16x16x32_f16(
            af[mt], bfr[nt], acc[mt][nt], 0, 0, 0);
  }
  __syncthreads();   // Ep aliases As/Bs: drain frag reads before epilogue

  // epilogue: C/D frag mapping row(m) = fq*4+reg, col(n) = fm
  if (F32OUT) {
    float* Cd = (float*)Cdv + (size_t)blockIdx.z * sC;
    #pragma unroll
    for (int mt = 0; mt < 4; ++mt) {
      float bv4[4];
      #pragma unroll
      for (int r = 0; r < 4; ++r)
        bv4[r] = bias[m0 + mh + mt * 16 + fq * 4 + r];
      #pragma unroll
      for (int nt = 0; nt < 4; ++nt) {
        int col = n0 + nh + nt * 16 + fm;
        #pragma unroll
        for (int r = 0; r < 4; ++r) {
          int row = m0 + mh + mt * 16 + fq * 4 + r;
          Cd[(size_t)row * N + col] = acc[mt][nt][r] + bv4[r];
        }
      }
    }
  } else {
    f16_t* Cd = (f16_t*)Cdv + (size_t)blockIdx.z * sC;
    #pragma unroll
    for (int mt = 0; mt < 4; ++mt) {
      float bv4[4];
      #pragma unroll
      for (int r = 0; r < 4; ++r)
        bv4[r] = bias[m0 + mh + mt * 16 + fq * 4 + r];
      #pragma unroll
      for (int nt = 0; nt < 4; ++nt) {
        int col = nh + nt * 16 + fm;
        #pragma unroll
        for (int r = 0; r < 4; ++r) {
          int row = mh + mt * 16 + fq * 4 + r;
          sh.Ep[row][col] = (f16_t)(acc[mt][nt][r] + bv4[r]);
        }
      }
    }
    __syncthreads();
    #pragma unroll
    for (int i = 0; i < 16; ++i) {
      int chunk = i * 256 + t;
      int row = chunk >> 5, c8 = chunk & 31;
      uint2 val = *(const uint2*)&sh.Ep[row][c8 * 4];
      *(uint2*)&Cd[(size_t)(m0 + row) * N + n0 + c8 * 4] = val;
    }
  }
}

// ---------------------------------------------------------------------------
// Attention v5: fused transpose with the FAITHFUL-RESHAPE mapping.
// qkv (z,3,D,L) f16 -> att2T[z][ll][dd] f16 where for value (h, l, d):
//   u  = l*64 + d   (within batch-head flat [h][l][d] layout)
//   ll = u & 2047,  dd = h*64 + (u >> 11)
// Block (h, l-chunk of 256): j = lane>>3 is lane-constant; stage tile2[ll][j],
// then each row ll is one aligned 16 B chunk -> uint4 store at col h*64+8*chi.
// ---------------------------------------------------------------------------
template <bool EDGE>
__global__ __launch_bounds__(256) void _MSA1_kattn5(const f16_t* __restrict__ qkv,
                                                    f16_t* __restrict__ attT,
                                                    int xmul, int xadd) {
  const int t = threadIdx.x;
  const int lane = t & 63;
  const int wid = __builtin_amdgcn_readfirstlane(t >> 6);
  const int h = blockIdx.y, b = blockIdx.z;
  const int chi = blockIdx.x * xmul + xadd;      // l-chunk index 0..7
  const int lbase = chi * 256;
  const int l0 = lbase + lane * 4;
  const size_t plane = (size_t)D_ * L_;
  const f16_t* base = qkv + (size_t)b * 3 * plane;

  __shared__ uint2 sred[4][3][64];
  __shared__ __align__(16) f16_t tile2[2048][8];

  const f16_t* qp = base + (size_t)(h * 64 + wid * 16) * L_ + l0;
  const f16_t* kpl = base + plane;
  const f16_t* vpl = base + 2 * plane;
  const int g0 = h * 192 + wid * 48;

  // ---- pass 1: partial scores (this wave's 16 d), 4 l per lane ----
  f16x2 sLo[3], sHi[3];
  #pragma unroll
  for (int w = 0; w < 3; ++w) { f16x2 z = {(f16_t)0, (f16_t)0}; sLo[w] = z; sHi[w] = z; }

  #pragma unroll
  for (int dd = 0; dd < 16; ++dd) {
    uint2 qw = *(const uint2*)(qp + (size_t)dd * L_);
    f16x2 qlo = bc2(qw.x), qhi = bc2(qw.y);
    #pragma unroll
    for (int w = 0; w < 3; ++w) {
      int g = g0 + 3 * dd + w;
      int c = g & 1023;
      int o = (g >> 10) - 1;
      uint2 kw = *(const uint2*)(kpl + (size_t)c * L_ + (l0 + o));
      if (EDGE) {
        if (o < 0 && l0 == 0) kw.x &= 0xFFFF0000u;
        if (o > 0 && l0 == 2044) kw.y &= 0x0000FFFFu;
      }
      sLo[w] = bc2(kw.x) * qlo + sLo[w];
      sHi[w] = bc2(kw.y) * qhi + sHi[w];
    }
  }
  #pragma unroll
  for (int w = 0; w < 3; ++w) {
    uint2 v; v.x = cb2(sLo[w]); v.y = cb2(sHi[w]);
    sred[wid][w][lane] = v;
  }
  __syncthreads();

  // ---- cross-wave reduce + softmax (each lane: its own 4 l) ----
  float sc[4][3];
  #pragma unroll
  for (int j = 0; j < 3; ++j) {
    uint2 r0 = sred[0][j][lane], r1 = sred[1][j][lane];
    uint2 r2 = sred[2][j][lane], r3 = sred[3][j][lane];
    f16x2 lo = (bc2(r0.x) + bc2(r1.x)) + (bc2(r2.x) + bc2(r3.x));
    f16x2 hi = (bc2(r0.y) + bc2(r1.y)) + (bc2(r2.y) + bc2(r3.y));
    sc[0][j] = (float)lo.x * 0.125f;
    sc[1][j] = (float)lo.y * 0.125f;
    sc[2][j] = (float)hi.x * 0.125f;
    sc[3][j] = (float)hi.y * 0.125f;
  }
  f16_t ef[4][3];
  #pragma unroll
  for (int li = 0; li < 4; ++li) {
    float mx = fmaxf(sc[li][0], fmaxf(sc[li][1], sc[li][2]));
    float e0 = __expf(sc[li][0] - mx), e1 = __expf(sc[li][1] - mx), e2 = __expf(sc[li][2] - mx);
    float inv = 1.f / (e0 + e1 + e2);
    ef[li][0] = (f16_t)(e0 * inv); ef[li][1] = (f16_t)(e1 * inv); ef[li][2] = (f16_t)(e2 * inv);
  }
  f16x2 eLo[3], eHi[3];
  #pragma unroll
  for (int w = 0; w < 3; ++w) {
    f16x2 a = {ef[0][w], ef[1][w]}; eLo[w] = a;
    f16x2 b2 = {ef[2][w], ef[3][w]}; eHi[w] = b2;
  }

  // ---- pass 2: weighted V sum; write tile2[ll][j] ----
  // ll = (lane&7)*256 + li*64 + wid*16 + dd ; j = lane>>3
  const int llb = (lane & 7) * 256 + wid * 16;
  const int jcol = lane >> 3;
  #pragma unroll
  for (int dd = 0; dd < 16; ++dd) {
    f16x2 aLo = {(f16_t)0, (f16_t)0}, aHi = {(f16_t)0, (f16_t)0};
    #pragma unroll
    for (int w = 0; w < 3; ++w) {
      int g = g0 + 3 * dd + w;
      int c = g & 1023;
      int o = (g >> 10) - 1;
      uint2 vw = *(const uint2*)(vpl + (size_t)c * L_ + (l0 + o));
      if (EDGE) {
        if (o < 0 && l0 == 0) vw.x &= 0xFFFF0000u;
        if (o > 0 && l0 == 2044) vw.y &= 0x0000FFFFu;
      }
      aLo = bc2(vw.x) * eLo[w] + aLo;
      aHi = bc2(vw.y) * eHi[w] + aHi;
    }
    const int llq = llb + dd;
    tile2[llq +   0][jcol] = aLo.x;   // li = 0
    tile2[llq +  64][jcol] = aLo.y;   // li = 1
    tile2[llq + 128][jcol] = aHi.x;   // li = 2
    tile2[llq + 192][jcol] = aHi.y;   // li = 3
  }
  __syncthreads();

  // ---- store: row ll -> 16 B at att2T[b][ll][h*64 + 8*chi .. +8) ----
  f16_t* ob = attT + (size_t)b * L_ * D_ + h * 64 + chi * 8;
  #pragma unroll
  for (int i = 0; i < 8; ++i) {
    int ll = i * 256 + t;
    uint4 val = *(const uint4*)&tile2[ll][0];
    *(uint4*)(ob + (size_t)ll * D_) = val;
  }
}

// ---------------------------------------------------------------------------
extern "C" void kernel_launch(void* const* d_in, const int* in_sizes, int n_in,
                              void* d_out, int out_size, void* d_ws, size_t ws_size,
                              hipStream_t stream) {
  (void)in_sizes; (void)n_in; (void)out_size;
  const float* x  = (const float*)d_in[0];
  const float* wq = (const float*)d_in[1];
  const float* bq = (const float*)d_in[2];
  const float* wk = (const float*)d_in[3];
  const float* bk = (const float*)d_in[4];
  const float* wv = (const float*)d_in[5];
  const float* bv = (const float*)d_in[6];
  const float* wo = (const float*)d_in[7];
  const float* bo = (const float*)d_in[8];
  float* out = (float*)d_out;
  char* ws = (char*)d_ws;

  f16_t* wT3   = (f16_t*)(ws);                 // 3x(1024x512) f16 = 3,145,728 B
  f16_t* woT   = (f16_t*)(ws + 3145728);       // (512x1024)  f16 = 1,048,576 B
  float* bias3 = (float*) (ws + 4194304);      // 3072 f32 (pad to 16,384)
  const size_t SHARED_END = 4210688;

  _MSA1_kprep<<<dim3(129, 4), dim3(256), 0, stream>>>(
      wq, wk, wv, wo, bq, bk, bv, wT3, woT, bias3);

  if (ws_size >= 155205632ull) {
    // ---------- batched-z path: xT 16.7MB + qkv 100.7MB + att2T 33.5MB ----
    f16_t* xT    = (f16_t*)(ws + SHARED_END);
    f16_t* qkv   = xT + 8388608ull;
    f16_t* att2T = qkv + 50331648ull;

    _MSA1_ktransf2h<<<dim3(32, 8, B_), dim3(256), 0, stream>>>(x, xT, 512, 2048);
    _MSA1_kgemm<false, 512><<<dim3(16, 24, B_), dim3(256), 0, stream>>>(
        wT3, xT, bias3, qkv, 3072, 2048,
        0L, (long)(2048 * 512), (long)(3072 * 2048));
    _MSA1_kattn5<false><<<dim3(6, 16, B_), dim3(256), 0, stream>>>(qkv, att2T, 1, 1);
    _MSA1_kattn5<true><<<dim3(2, 16, B_), dim3(256), 0, stream>>>(qkv, att2T, 7, 0);
    _MSA1_kgemm<true, 1024><<<dim3(16, 4, B_), dim3(256), 0, stream>>>(
        woT, att2T, bo, out, 512, 2048,
        0L, (long)(2048 * 1024), (long)(512 * 2048));
  } else {
    // ---------- per-batch slab path ----------
    f16_t* xTb    = (f16_t*)(ws + SHARED_END);
    f16_t* qkvb   = xTb + 1048576ull;
    f16_t* att2Tb = qkvb + 6291456ull;
    for (int b = 0; b < B_; ++b) {
      const float* xb = x + (size_t)b * C_ * L_;
      _MSA1_ktransf2h<<<dim3(32, 8, 1), dim3(256), 0, stream>>>(xb, xTb, 512, 2048);
      _MSA1_kgemm<false, 512><<<dim3(16, 24, 1), dim3(256), 0, stream>>>(
          wT3, xTb, bias3, qkvb, 3072, 2048, 0L, 0L, 0L);
      _MSA1_kattn5<false><<<dim3(6, 16, 1), dim3(256), 0, stream>>>(qkvb, att2Tb, 1, 1);
      _MSA1_kattn5<true><<<dim3(2, 16, 1), dim3(256), 0, stream>>>(qkvb, att2Tb, 7, 0);
      _MSA1_kgemm<true, 1024><<<dim3(16, 4, 1), dim3(256), 0, stream>>>(
          woT, att2Tb, bo, out + (size_t)b * C_ * L_, 512, 2048, 0L, 0L, 0L);
    }
  }
}

// Round 9
// 272.786 us; speedup vs baseline: 1.0459x; 1.0459x over previous
//
#include <hip/hip_runtime.h>

typedef _Float16 f16_t;
typedef _Float16 f16x2 __attribute__((ext_vector_type(2)));
typedef _Float16 f16x8 __attribute__((ext_vector_type(8)));
typedef float floatx4 __attribute__((ext_vector_type(4)));
typedef unsigned int u32;
typedef const __attribute__((address_space(1))) unsigned int* gptr_as1;
typedef __attribute__((address_space(3))) unsigned int* lptr_as3;

#define B_ 8
#define C_ 512
#define L_ 2048
#define D_ 1024
#define H_ 16

static __device__ __forceinline__ f16x2 bc2(u32 v) { return __builtin_bit_cast(f16x2, v); }
static __device__ __forceinline__ u32 cb2(f16x2 v) { return __builtin_bit_cast(u32, v); }

// ---------------------------------------------------------------------------
// Transpose + f32->f16 convert: in (R,C) f32 -> out (C,R) f16, batched z.
// ---------------------------------------------------------------------------
__global__ __launch_bounds__(256) void _MSA1_ktransf2h(const float* __restrict__ in,
                                                       f16_t* __restrict__ out,
                                                       int R, int C) {
  size_t zoff = (size_t)blockIdx.z * R * C;
  in += zoff; out += zoff;
  __shared__ f16_t tile[64][65];
  int r0 = blockIdx.y * 64, c0 = blockIdx.x * 64;
  int t = threadIdx.x;
  #pragma unroll
  for (int i = 0; i < 16; ++i) {
    int idx = t + i * 256;
    int r = idx >> 6, c = idx & 63;
    tile[c][r] = (f16_t)in[(size_t)(r0 + r) * C + (c0 + c)];
  }
  __syncthreads();
  #pragma unroll
  for (int i = 0; i < 16; ++i) {
    int idx = t + i * 256;
    int r = idx >> 6, c = idx & 63;
    out[(size_t)(c0 + r) * R + (r0 + c)] = tile[r][c];
  }
}

// ---------------------------------------------------------------------------
// Fused prep: all 4 weight transposes (f32->f16) + bias concat, one launch.
// ---------------------------------------------------------------------------
__global__ __launch_bounds__(256) void _MSA1_kprep(
    const float* __restrict__ wq, const float* __restrict__ wk,
    const float* __restrict__ wv, const float* __restrict__ wo,
    const float* __restrict__ bq, const float* __restrict__ bk,
    const float* __restrict__ bv,
    f16_t* __restrict__ wT3, f16_t* __restrict__ woT, float* __restrict__ bias3) {
  const int x = blockIdx.x, y = blockIdx.y;
  const int t = threadIdx.x;
  if (x == 128) {
    if (y == 0) {
      for (int i = t; i < 1024; i += 256) {
        bias3[i] = bq[i];
        bias3[1024 + i] = bk[i];
        bias3[2048 + i] = bv[i];
      }
    }
    return;
  }
  __shared__ f16_t tile[64][65];
  const float* in; f16_t* out; int R, C, r0, c0;
  if (y < 3) {
    R = 512; C = 1024;
    in = (y == 0) ? wq : (y == 1) ? wk : wv;
    out = wT3 + (size_t)y * 524288;
    r0 = (x >> 4) * 64; c0 = (x & 15) * 64;
  } else {
    R = 1024; C = 512;
    in = wo; out = woT;
    r0 = (x >> 3) * 64; c0 = (x & 7) * 64;
  }
  #pragma unroll
  for (int i = 0; i < 16; ++i) {
    int idx = t + i * 256;
    int r = idx >> 6, c = idx & 63;
    tile[c][r] = (f16_t)in[(size_t)(r0 + r) * C + (c0 + c)];
  }
  __syncthreads();
  #pragma unroll
  for (int i = 0; i < 16; ++i) {
    int idx = t + i * 256;
    int r = idx >> 6, c = idx & 63;
    out[(size_t)(c0 + r) * R + (r0 + c)] = tile[r][c];
  }
}

// ---------------------------------------------------------------------------
// GEMM: out[m][n] = sum_k A[m][k]*Bt[n][k] + bias[m]
// 128x128 tile, BK=32, 4 waves x 64x64, 16x16x32 f16 MFMA, global_load_lds
// width-16 staging. Epilogue repack now runs in TWO 64-row halves so the
// union LDS is max(16 KB staging, 16.9 KB Ep) -> 6 blocks/CU (VGPR-limited)
// instead of 4 (was 33.8 KB). More resident waves hide the barrier drains.
// ---------------------------------------------------------------------------
template <bool F32OUT, int K>
__global__ __launch_bounds__(256) void _MSA1_kgemm(
    const f16_t* __restrict__ A, const f16_t* __restrict__ Bt,
    const float* __restrict__ bias, void* __restrict__ Cdv,
    int M, int N, long sA, long sB, long sC) {
  A  += (size_t)blockIdx.z * sA;
  Bt += (size_t)blockIdx.z * sB;
  const int m0 = blockIdx.y * 128, n0 = blockIdx.x * 128;

  union ShU {
    struct { f16_t As[128][32]; f16_t Bs[128][32]; } ab;   // 16 KB
    f16_t Ep[F32OUT ? 1 : 64][132];                         // 16.9 KB (f16 path)
  };
  __shared__ ShU sh;

  const int t = threadIdx.x;
  const int lane = t & 63, w = t >> 6;
  const int mh = (w & 1) * 64, nh = (w >> 1) * 64;
  const int fm = lane & 15, fq = lane >> 4;
  const int srcoff = ((t & 3) ^ ((t >> 2) & 3)) * 8;
  const int colf = ((fq ^ (fm & 3)) * 8);

  floatx4 acc[4][4];
  #pragma unroll
  for (int i = 0; i < 4; ++i)
    #pragma unroll
    for (int j = 0; j < 4; ++j) {
      floatx4 z4 = {0.f, 0.f, 0.f, 0.f};
      acc[i][j] = z4;
    }

  for (int kt = 0; kt < K; kt += 32) {
    __syncthreads();
    #pragma unroll
    for (int j = 0; j < 2; ++j) {
      int chunk = j * 256 + t;
      int r = chunk >> 2;
      const f16_t* ga = A + (size_t)(m0 + r) * K + kt + srcoff;
      __builtin_amdgcn_global_load_lds((gptr_as1)(const void*)ga,
          (lptr_as3)(void*)((char*)&sh.ab.As[0][0] + j * 4096 + w * 1024), 16, 0, 0);
      const f16_t* gb = Bt + (size_t)(n0 + r) * K + kt + srcoff;
      __builtin_amdgcn_global_load_lds((gptr_as1)(const void*)gb,
          (lptr_as3)(void*)((char*)&sh.ab.Bs[0][0] + j * 4096 + w * 1024), 16, 0, 0);
    }
    __syncthreads();

    f16x8 af[4], bfr[4];
    #pragma unroll
    for (int mt = 0; mt < 4; ++mt)
      af[mt] = *(const f16x8*)&sh.ab.As[mh + mt * 16 + fm][colf];
    #pragma unroll
    for (int nt = 0; nt < 4; ++nt)
      bfr[nt] = *(const f16x8*)&sh.ab.Bs[nh + nt * 16 + fm][colf];
    #pragma unroll
    for (int mt = 0; mt < 4; ++mt)
      #pragma unroll
      for (int nt = 0; nt < 4; ++nt)
        acc[mt][nt] = __builtin_amdgcn_mfma_f32_16x16x32_f16(
            af[mt], bfr[nt], acc[mt][nt], 0, 0, 0);
  }
  __syncthreads();   // drain frag reads before Ep reuse / epilogue

  // epilogue: C/D frag mapping row(m) = fq*4+reg, col(n) = fm
  if (F32OUT) {
    float* Cd = (float*)Cdv + (size_t)blockIdx.z * sC;
    #pragma unroll
    for (int mt = 0; mt < 4; ++mt) {
      float bv4[4];
      #pragma unroll
      for (int r = 0; r < 4; ++r)
        bv4[r] = bias[m0 + mh + mt * 16 + fq * 4 + r];
      #pragma unroll
      for (int nt = 0; nt < 4; ++nt) {
        int col = n0 + nh + nt * 16 + fm;
        #pragma unroll
        for (int r = 0; r < 4; ++r) {
          int row = m0 + mh + mt * 16 + fq * 4 + r;
          Cd[(size_t)row * N + col] = acc[mt][nt][r] + bv4[r];
        }
      }
    }
  } else {
    f16_t* Cd = (f16_t*)Cdv + (size_t)blockIdx.z * sC;
    #pragma unroll
    for (int half = 0; half < 2; ++half) {
      if (half) __syncthreads();           // Ep reused between halves
      if (mh == half * 64) {               // waves whose rows are in this half
        #pragma unroll
        for (int mt = 0; mt < 4; ++mt) {
          float bv4[4];
          #pragma unroll
          for (int r = 0; r < 4; ++r)
            bv4[r] = bias[m0 + half * 64 + mt * 16 + fq * 4 + r];
          #pragma unroll
          for (int nt = 0; nt < 4; ++nt) {
            int col = nh + nt * 16 + fm;
            #pragma unroll
            for (int r = 0; r < 4; ++r) {
              int row = mt * 16 + fq * 4 + r;     // 0..63 within half
              sh.Ep[row][col] = (f16_t)(acc[mt][nt][r] + bv4[r]);
            }
          }
        }
      }
      __syncthreads();
      #pragma unroll
      for (int i = 0; i < 8; ++i) {
        int chunk = i * 256 + t;           // 2048 x 8B chunks, rows 0..63
        int row = chunk >> 5, c8 = chunk & 31;
        uint2 val = *(const uint2*)&sh.Ep[row][c8 * 4];
        *(uint2*)&Cd[(size_t)(m0 + half * 64 + row) * N + n0 + c8 * 4] = val;
      }
    }
  }
}

// ---------------------------------------------------------------------------
// Attention v6: merged interior+edge (per-lane predication), fused faithful-
// reshape transpose store.  Grid (hb=128, chi=8): sibling chi-blocks of one
// (b,h) have linear ids identical mod 8 -> same XCD (round-robin heuristic),
// so their 16 B column segments merge into full 128 B lines in that L2.
//   u = l*64 + d ; ll = u & 2047 ; dd = h*64 + (u >> 11)
// ---------------------------------------------------------------------------
__global__ __launch_bounds__(256) void _MSA1_kattn6(const f16_t* __restrict__ qkv,
                                                    f16_t* __restrict__ attT) {
  const int t = threadIdx.x;
  const int lane = t & 63;
  const int wid = __builtin_amdgcn_readfirstlane(t >> 6);
  const int hb = blockIdx.x;
  const int h = hb & 15, b = hb >> 4;
  const int chi = blockIdx.y;                 // l-chunk 0..7
  const int lbase = chi * 256;
  const int l0 = lbase + lane * 4;
  const size_t plane = (size_t)D_ * L_;
  const f16_t* base = qkv + (size_t)b * 3 * plane;

  __shared__ uint2 sred[4][3][64];
  __shared__ __align__(16) f16_t tile2[2048][8];

  const f16_t* qp = base + (size_t)(h * 64 + wid * 16) * L_ + l0;
  const f16_t* kpl = base + plane;
  const f16_t* vpl = base + 2 * plane;
  const int g0 = h * 192 + wid * 48;

  // ---- pass 1: partial scores (this wave's 16 d), 4 l per lane ----
  f16x2 sLo[3], sHi[3];
  #pragma unroll
  for (int w = 0; w < 3; ++w) { f16x2 z = {(f16_t)0, (f16_t)0}; sLo[w] = z; sHi[w] = z; }

  #pragma unroll
  for (int dd = 0; dd < 16; ++dd) {
    uint2 qw = *(const uint2*)(qp + (size_t)dd * L_);
    f16x2 qlo = bc2(qw.x), qhi = bc2(qw.y);
    #pragma unroll
    for (int w = 0; w < 3; ++w) {
      int g = g0 + 3 * dd + w;
      int c = g & 1023;
      int o = (g >> 10) - 1;
      uint2 kw = *(const uint2*)(kpl + (size_t)c * L_ + (l0 + o));
      if (o < 0 && l0 == 0) kw.x &= 0xFFFF0000u;
      if (o > 0 && l0 == 2044) kw.y &= 0x0000FFFFu;
      sLo[w] = bc2(kw.x) * qlo + sLo[w];
      sHi[w] = bc2(kw.y) * qhi + sHi[w];
    }
  }
  #pragma unroll
  for (int w = 0; w < 3; ++w) {
    uint2 v; v.x = cb2(sLo[w]); v.y = cb2(sHi[w]);
    sred[wid][w][lane] = v;
  }
  __syncthreads();

  // ---- cross-wave reduce + softmax (each lane: its own 4 l) ----
  float sc[4][3];
  #pragma unroll
  for (int j = 0; j < 3; ++j) {
    uint2 r0 = sred[0][j][lane], r1 = sred[1][j][lane];
    uint2 r2 = sred[2][j][lane], r3 = sred[3][j][lane];
    f16x2 lo = (bc2(r0.x) + bc2(r1.x)) + (bc2(r2.x) + bc2(r3.x));
    f16x2 hi = (bc2(r0.y) + bc2(r1.y)) + (bc2(r2.y) + bc2(r3.y));
    sc[0][j] = (float)lo.x * 0.125f;
    sc[1][j] = (float)lo.y * 0.125f;
    sc[2][j] = (float)hi.x * 0.125f;
    sc[3][j] = (float)hi.y * 0.125f;
  }
  f16_t ef[4][3];
  #pragma unroll
  for (int li = 0; li < 4; ++li) {
    float mx = fmaxf(sc[li][0], fmaxf(sc[li][1], sc[li][2]));
    float e0 = __expf(sc[li][0] - mx), e1 = __expf(sc[li][1] - mx), e2 = __expf(sc[li][2] - mx);
    float inv = 1.f / (e0 + e1 + e2);
    ef[li][0] = (f16_t)(e0 * inv); ef[li][1] = (f16_t)(e1 * inv); ef[li][2] = (f16_t)(e2 * inv);
  }
  f16x2 eLo[3], eHi[3];
  #pragma unroll
  for (int w = 0; w < 3; ++w) {
    f16x2 a = {ef[0][w], ef[1][w]}; eLo[w] = a;
    f16x2 b2 = {ef[2][w], ef[3][w]}; eHi[w] = b2;
  }

  // ---- pass 2: weighted V sum; write tile2[ll][j] ----
  // ll = (lane&7)*256 + li*64 + wid*16 + dd ; j = lane>>3
  const int llb = (lane & 7) * 256 + wid * 16;
  const int jcol = lane >> 3;
  #pragma unroll
  for (int dd = 0; dd < 16; ++dd) {
    f16x2 aLo = {(f16_t)0, (f16_t)0}, aHi = {(f16_t)0, (f16_t)0};
    #pragma unroll
    for (int w = 0; w < 3; ++w) {
      int g = g0 + 3 * dd + w;
      int c = g & 1023;
      int o = (g >> 10) - 1;
      uint2 vw = *(const uint2*)(vpl + (size_t)c * L_ + (l0 + o));
      if (o < 0 && l0 == 0) vw.x &= 0xFFFF0000u;
      if (o > 0 && l0 == 2044) vw.y &= 0x0000FFFFu;
      aLo = bc2(vw.x) * eLo[w] + aLo;
      aHi = bc2(vw.y) * eHi[w] + aHi;
    }
    const int llq = llb + dd;
    tile2[llq +   0][jcol] = aLo.x;   // li = 0
    tile2[llq +  64][jcol] = aLo.y;   // li = 1
    tile2[llq + 128][jcol] = aHi.x;   // li = 2
    tile2[llq + 192][jcol] = aHi.y;   // li = 3
  }
  __syncthreads();

  // ---- store: row ll -> 16 B at att2T[b][ll][h*64 + 8*chi .. +8) ----
  f16_t* ob = attT + (size_t)b * L_ * D_ + h * 64 + chi * 8;
  #pragma unroll
  for (int i = 0; i < 8; ++i) {
    int ll = i * 256 + t;
    uint4 val = *(const uint4*)&tile2[ll][0];
    *(uint4*)(ob + (size_t)ll * D_) = val;
  }
}

// ---------------------------------------------------------------------------
extern "C" void kernel_launch(void* const* d_in, const int* in_sizes, int n_in,
                              void* d_out, int out_size, void* d_ws, size_t ws_size,
                              hipStream_t stream) {
  (void)in_sizes; (void)n_in; (void)out_size;
  const float* x  = (const float*)d_in[0];
  const float* wq = (const float*)d_in[1];
  const float* bq = (const float*)d_in[2];
  const float* wk = (const float*)d_in[3];
  const float* bk = (const float*)d_in[4];
  const float* wv = (const float*)d_in[5];
  const float* bv = (const float*)d_in[6];
  const float* wo = (const float*)d_in[7];
  const float* bo = (const float*)d_in[8];
  float* out = (float*)d_out;
  char* ws = (char*)d_ws;

  f16_t* wT3   = (f16_t*)(ws);                 // 3x(1024x512) f16 = 3,145,728 B
  f16_t* woT   = (f16_t*)(ws + 3145728);       // (512x1024)  f16 = 1,048,576 B
  float* bias3 = (float*) (ws + 4194304);      // 3072 f32 (pad to 16,384)
  const size_t SHARED_END = 4210688;

  _MSA1_kprep<<<dim3(129, 4), dim3(256), 0, stream>>>(
      wq, wk, wv, wo, bq, bk, bv, wT3, woT, bias3);

  if (ws_size >= 155205632ull) {
    // ---------- batched-z path: xT 16.7MB + qkv 100.7MB + att2T 33.5MB ----
    f16_t* xT    = (f16_t*)(ws + SHARED_END);
    f16_t* qkv   = xT + 8388608ull;
    f16_t* att2T = qkv + 50331648ull;

    _MSA1_ktransf2h<<<dim3(32, 8, B_), dim3(256), 0, stream>>>(x, xT, 512, 2048);
    _MSA1_kgemm<false, 512><<<dim3(16, 24, B_), dim3(256), 0, stream>>>(
        wT3, xT, bias3, qkv, 3072, 2048,
        0L, (long)(2048 * 512), (long)(3072 * 2048));
    _MSA1_kattn6<<<dim3(128, 8), dim3(256), 0, stream>>>(qkv, att2T);
    _MSA1_kgemm<true, 1024><<<dim3(16, 4, B_), dim3(256), 0, stream>>>(
        woT, att2T, bo, out, 512, 2048,
        0L, (long)(2048 * 1024), (long)(512 * 2048));
  } else {
    // ---------- per-batch slab path ----------
    f16_t* xTb    = (f16_t*)(ws + SHARED_END);
    f16_t* qkvb   = xTb + 1048576ull;
    f16_t* att2Tb = qkvb + 6291456ull;
    for (int b = 0; b < B_; ++b) {
      const float* xb = x + (size_t)b * C_ * L_;
      _MSA1_ktransf2h<<<dim3(32, 8, 1), dim3(256), 0, stream>>>(xb, xTb, 512, 2048);
      _MSA1_kgemm<false, 512><<<dim3(16, 24, 1), dim3(256), 0, stream>>>(
          wT3, xTb, bias3, qkvb, 3072, 2048, 0L, 0L, 0L);
      _MSA1_kattn6<<<dim3(16, 8), dim3(256), 0, stream>>>(qkvb, att2Tb);
      _MSA1_kgemm<true, 1024><<<dim3(16, 4, 1), dim3(256), 0, stream>>>(
          woT, att2Tb, bo, out + (size_t)b * C_ * L_, 512, 2048, 0L, 0L, 0L);
    }
  }
}